// Round 1
// baseline (714.185 us; speedup 1.0000x reference)
//
#include <hip/hip_runtime.h>
#include <hip/hip_bf16.h>

#define N_NODES 50000
#define E_EDGES 800000
#define IN_DIM  128
#define HIDDEN  96
#define HEADS   4
#define HEAD_DIM 24
#define NEG_SLOPE 0.2f

// ---------------- CSR build ----------------

__global__ void k_hist(const int* __restrict__ dst, int* __restrict__ deg) {
    int e = blockIdx.x * 256 + threadIdx.x;
    if (e < E_EDGES) atomicAdd(&deg[dst[e]], 1);
}

__global__ __launch_bounds__(1024) void k_scan(const int* __restrict__ deg,
                                               int* __restrict__ off, int n) {
    __shared__ int buf[1024];
    __shared__ int carryS;
    if (threadIdx.x == 0) carryS = 0;
    __syncthreads();
    const int CH = 8;
    for (int base = 0; base < n; base += 1024 * CH) {
        int v[CH];
        int s = 0;
        int i0 = base + threadIdx.x * CH;
#pragma unroll
        for (int j = 0; j < CH; ++j) {
            int i = i0 + j;
            v[j] = (i < n) ? deg[i] : 0;
            s += v[j];
        }
        buf[threadIdx.x] = s;
        __syncthreads();
        for (int st = 1; st < 1024; st <<= 1) {
            int t = (threadIdx.x >= st) ? buf[threadIdx.x - st] : 0;
            __syncthreads();
            buf[threadIdx.x] += t;
            __syncthreads();
        }
        int run = carryS + buf[threadIdx.x] - s; // exclusive prefix for this chunk
#pragma unroll
        for (int j = 0; j < CH; ++j) {
            int i = i0 + j;
            if (i < n) off[i] = run;
            run += v[j];
        }
        __syncthreads();
        if (threadIdx.x == 1023) carryS = carryS + buf[1023];
        __syncthreads();
    }
    if (threadIdx.x == 0) off[n] = carryS;
}

__global__ void k_fill(const int* __restrict__ src, const int* __restrict__ dst,
                       const int* __restrict__ off, int* __restrict__ cursor,
                       int* __restrict__ ssrc, int* __restrict__ sdst) {
    int e = blockIdx.x * 256 + threadIdx.x;
    if (e < E_EDGES) {
        int d = dst[e];
        int p = off[d] + atomicAdd(&cursor[d], 1);
        ssrc[p] = src[e];
        sdst[p] = d;
    }
}

// ---------------- per-layer kernels ----------------

// feat[N,96] = h[N,K] @ W[K,96]
template <int K>
__global__ __launch_bounds__(192) void k_gemm(const float* __restrict__ h,
                                              const float* __restrict__ W,
                                              float* __restrict__ feat, int n) {
    __shared__ float hl[32 * K];
    int node0 = blockIdx.x * 32;
    int total4 = 32 * K / 4;
    for (int idx = threadIdx.x; idx < total4; idx += 192) {
        int node = idx / (K / 4);
        int koff = (idx % (K / 4)) * 4;
        float4 v = make_float4(0.f, 0.f, 0.f, 0.f);
        if (node0 + node < n)
            v = *(const float4*)(&h[(size_t)(node0 + node) * K + koff]);
        *(float4*)(&hl[node * K + koff]) = v;
    }
    __syncthreads();
    int grp = threadIdx.x / 96; // 0 or 1
    int c = threadIdx.x % 96;
    int nodeBase = grp * 16;
    float acc[16];
#pragma unroll
    for (int i = 0; i < 16; ++i) acc[i] = 0.f;
    for (int k = 0; k < K; k += 4) {
        float w0 = W[(k + 0) * 96 + c];
        float w1 = W[(k + 1) * 96 + c];
        float w2 = W[(k + 2) * 96 + c];
        float w3 = W[(k + 3) * 96 + c];
#pragma unroll
        for (int i = 0; i < 16; ++i) {
            float4 hv = *(const float4*)(&hl[(nodeBase + i) * K + k]);
            acc[i] = fmaf(hv.x, w0, acc[i]);
            acc[i] = fmaf(hv.y, w1, acc[i]);
            acc[i] = fmaf(hv.z, w2, acc[i]);
            acc[i] = fmaf(hv.w, w3, acc[i]);
        }
    }
#pragma unroll
    for (int i = 0; i < 16; ++i) {
        int node = node0 + nodeBase + i;
        if (node < n) feat[(size_t)node * 96 + c] = acc[i];
    }
}

// el/er[N,4] = sum_d feat[n,h,d] * a_{l/r}[h,d]
__global__ void k_elr(const float* __restrict__ feat, const float* __restrict__ al,
                      const float* __restrict__ ar, float* __restrict__ el,
                      float* __restrict__ er, int n) {
    int idx = blockIdx.x * blockDim.x + threadIdx.x; // node*4 + h
    if (idx >= n * 4) return;
    int node = idx >> 2, h = idx & 3;
    const float* f = &feat[(size_t)node * 96 + h * 24];
    float sl = 0.f, sr = 0.f;
#pragma unroll
    for (int d = 0; d < 24; ++d) {
        float v = f[d];
        sl = fmaf(v, al[h * 24 + d], sl);
        sr = fmaf(v, ar[h * 24 + d], sr);
    }
    el[idx] = sl;
    er[idx] = sr;
}

// per sorted edge: logits = leaky_relu(el[src] + er[dst])
__global__ void k_logits(const int* __restrict__ ssrc, const int* __restrict__ sdst,
                         const float* __restrict__ el, const float* __restrict__ er,
                         float* __restrict__ logits) {
    int p = blockIdx.x * 256 + threadIdx.x;
    if (p >= E_EDGES) return;
    int s = ssrc[p], d = sdst[p];
    float4 l = *(const float4*)&el[s * 4];
    float4 r = *(const float4*)&er[d * 4];
    float4 e;
    e.x = l.x + r.x; e.x = (e.x > 0.f) ? e.x : NEG_SLOPE * e.x;
    e.y = l.y + r.y; e.y = (e.y > 0.f) ? e.y : NEG_SLOPE * e.y;
    e.z = l.z + r.z; e.z = (e.z > 0.f) ? e.z : NEG_SLOPE * e.z;
    e.w = l.w + r.w; e.w = (e.w > 0.f) ? e.w : NEG_SLOPE * e.w;
    *(float4*)&logits[p * 4] = e;
}

// per-node softmax + weighted aggregation + bias + ELU
__global__ __launch_bounds__(128) void k_agg(const int* __restrict__ off,
                                             const int* __restrict__ ssrc,
                                             const float* __restrict__ logits,
                                             const float* __restrict__ feat,
                                             const float* __restrict__ bias,
                                             float* __restrict__ out) {
    int n = blockIdx.x;
    int start = off[n], end = off[n + 1];
    int tid = threadIdx.x;
    __shared__ float m[4], rden[4];
    __shared__ float red[128];
    __shared__ float alpha[32 * 4];
    __shared__ int slds[32];
    int h4 = tid & 3;

    // Phase 1a: per-head max
    float lm = -1e30f;
    for (int j = start + (tid >> 2); j < end; j += 32)
        lm = fmaxf(lm, logits[j * 4 + h4]);
    red[tid] = lm;
    __syncthreads();
    if (tid < 4) {
        float v = -1e30f;
        for (int i = tid; i < 128; i += 4) v = fmaxf(v, red[i]);
        m[tid] = v;
    }
    __syncthreads();
    // Phase 1b: per-head denom
    float ls = 0.f;
    for (int j = start + (tid >> 2); j < end; j += 32)
        ls += expf(logits[j * 4 + h4] - m[h4]);
    red[tid] = ls;
    __syncthreads();
    if (tid < 4) {
        float v = 0.f;
        for (int i = tid; i < 128; i += 4) v += red[i];
        rden[tid] = (v > 0.f) ? 1.f / v : 0.f;
    }
    __syncthreads();

    // Phase 2: accumulate channels
    int c = tid;
    int h = tid / 24; // valid when c < 96
    float acc = 0.f;
    for (int cb = start; cb < end; cb += 32) {
        int cn = min(32, end - cb);
        if (tid < cn * 4)
            alpha[tid] = expf(logits[(cb + (tid >> 2)) * 4 + h4] - m[h4]) * rden[h4];
        if (tid < cn) slds[tid] = ssrc[cb + tid];
        __syncthreads();
        if (c < 96) {
            for (int e = 0; e < cn; ++e)
                acc = fmaf(alpha[e * 4 + h], feat[(size_t)slds[e] * 96 + c], acc);
        }
        __syncthreads();
    }
    if (c < 96) {
        float v = acc + bias[c];
        out[(size_t)n * 96 + c] = (v > 0.f) ? v : (expf(v) - 1.f);
    }
}

// mean pool over nodes -> out[96]
__global__ __launch_bounds__(128) void k_pool(const float* __restrict__ h,
                                              float* __restrict__ out) {
    int tid = threadIdx.x;
    if (tid >= 96) return;
    float a = 0.f;
    for (int nrow = blockIdx.x; nrow < N_NODES; nrow += gridDim.x)
        a += h[(size_t)nrow * 96 + tid];
    atomicAdd(&out[tid], a * (1.0f / N_NODES));
}

// ---------------- launch ----------------

extern "C" void kernel_launch(void* const* d_in, const int* in_sizes, int n_in,
                              void* d_out, int out_size, void* d_ws, size_t ws_size,
                              hipStream_t stream) {
    const float* feats = (const float*)d_in[0];
    const int* src = (const int*)d_in[1];
    const int* dst = (const int*)d_in[2];

    char* p = (char*)d_ws;
    auto alloc = [&](size_t bytes) {
        void* r = (void*)p;
        p += (bytes + 255) & ~(size_t)255;
        return r;
    };
    float* A      = (float*)alloc((size_t)N_NODES * 96 * 4); // layer outputs (h)
    float* B      = (float*)alloc((size_t)N_NODES * 96 * 4); // feat = h@W
    float* el     = (float*)alloc((size_t)N_NODES * 4 * 4);
    float* er     = (float*)alloc((size_t)N_NODES * 4 * 4);
    float* logits = (float*)alloc((size_t)E_EDGES * 4 * 4);
    int* deg      = (int*)alloc((size_t)N_NODES * 4);
    int* cursor   = (int*)alloc((size_t)N_NODES * 4);
    int* off      = (int*)alloc((size_t)(N_NODES + 1) * 4);
    int* ssrc     = (int*)alloc((size_t)E_EDGES * 4);
    int* sdst     = (int*)alloc((size_t)E_EDGES * 4);

    // deg and cursor are adjacent: one memset clears both
    hipMemsetAsync(deg, 0, ((size_t)N_NODES * 4 + 255 & ~(size_t)255) + (size_t)N_NODES * 4, stream);
    hipMemsetAsync(d_out, 0, (size_t)out_size * 4, stream);

    // CSR build (by dst)
    k_hist<<<(E_EDGES + 255) / 256, 256, 0, stream>>>(dst, deg);
    k_scan<<<1, 1024, 0, stream>>>(deg, off, N_NODES);
    k_fill<<<(E_EDGES + 255) / 256, 256, 0, stream>>>(src, dst, off, cursor, ssrc, sdst);

    const float* hin = feats;
    for (int l = 0; l < 3; ++l) {
        const float* W  = (const float*)d_in[3 + 4 * l];
        const float* al = (const float*)d_in[4 + 4 * l];
        const float* ar = (const float*)d_in[5 + 4 * l];
        const float* bb = (const float*)d_in[6 + 4 * l];

        if (l == 0)
            k_gemm<IN_DIM><<<(N_NODES + 31) / 32, 192, 0, stream>>>(hin, W, B, N_NODES);
        else
            k_gemm<HIDDEN><<<(N_NODES + 31) / 32, 192, 0, stream>>>(hin, W, B, N_NODES);

        k_elr<<<(N_NODES * 4 + 255) / 256, 256, 0, stream>>>(B, al, ar, el, er, N_NODES);
        k_logits<<<(E_EDGES + 255) / 256, 256, 0, stream>>>(ssrc, sdst, el, er, logits);
        k_agg<<<N_NODES, 128, 0, stream>>>(off, ssrc, logits, B, bb, A);
        hin = A;
    }

    k_pool<<<256, 128, 0, stream>>>(A, (float*)d_out);
}

// Round 4
// 530.730 us; speedup vs baseline: 1.3457x; 1.3457x over previous
//
#include <hip/hip_runtime.h>
#include <hip/hip_bf16.h>

#define N_NODES 50000
#define E_EDGES 800000
#define IN_DIM  128
#define HIDDEN  96
#define HEADS   4
#define HEAD_DIM 24
#define NEG_SLOPE 0.2f
#define DEG_CAP 256

// ---------------- CSR build ----------------

__global__ void k_hist(const int* __restrict__ dst, int* __restrict__ deg) {
    int e = blockIdx.x * 256 + threadIdx.x;
    if (e < E_EDGES) atomicAdd(&deg[dst[e]], 1);
}

// block sums of deg
__global__ __launch_bounds__(256) void k_scan1(const int* __restrict__ deg,
                                               int* __restrict__ bsum, int n) {
    int i = blockIdx.x * 256 + threadIdx.x;
    int v = (i < n) ? deg[i] : 0;
#pragma unroll
    for (int s = 1; s < 64; s <<= 1) v += __shfl_xor(v, s);
    __shared__ int ws[4];
    if ((threadIdx.x & 63) == 0) ws[threadIdx.x >> 6] = v;
    __syncthreads();
    if (threadIdx.x == 0) bsum[blockIdx.x] = ws[0] + ws[1] + ws[2] + ws[3];
}

// exclusive scan of block sums (nb <= 256), single block
__global__ __launch_bounds__(256) void k_scan2(int* __restrict__ bsum, int nb) {
    int tid = threadIdx.x;
    int v = (tid < nb) ? bsum[tid] : 0;
    int lane = tid & 63, wv = tid >> 6;
    int x = v;
#pragma unroll
    for (int s = 1; s < 64; s <<= 1) {
        int t = __shfl_up(x, s);
        if (lane >= s) x += t;
    }
    __shared__ int wsum[4];
    if (lane == 63) wsum[wv] = x;
    __syncthreads();
    int add = 0;
    for (int w = 0; w < wv; ++w) add += wsum[w];
    x += add;
    if (tid < nb) bsum[tid] = x - v; // exclusive
}

// final offsets
__global__ __launch_bounds__(256) void k_scan3(const int* __restrict__ deg,
                                               const int* __restrict__ bsum,
                                               int* __restrict__ off, int n) {
    int tid = threadIdx.x;
    int i = blockIdx.x * 256 + tid;
    int v = (i < n) ? deg[i] : 0;
    int lane = tid & 63, wv = tid >> 6;
    int x = v;
#pragma unroll
    for (int s = 1; s < 64; s <<= 1) {
        int t = __shfl_up(x, s);
        if (lane >= s) x += t;
    }
    __shared__ int wsum[4];
    if (lane == 63) wsum[wv] = x;
    __syncthreads();
    int add = bsum[blockIdx.x];
    for (int w = 0; w < wv; ++w) add += wsum[w];
    if (i < n) off[i] = x - v + add;
    if (i == n - 1) off[n] = x + add;
}

__global__ void k_fill(const int* __restrict__ src, const int* __restrict__ dst,
                       const int* __restrict__ off, int* __restrict__ cursor,
                       int* __restrict__ ssrc) {
    int e = blockIdx.x * 256 + threadIdx.x;
    if (e < E_EDGES) {
        int d = dst[e];
        int p = off[d] + atomicAdd(&cursor[d], 1);
        ssrc[p] = src[e];
    }
}

// ---------------- per-layer kernels ----------------

// feat[N,96] = h[N,K] @ W[K,96]; 192 thr = 4 node-groups x 48 channel-pair threads
template <int K>
__global__ __launch_bounds__(192) void k_gemm(const float* __restrict__ h,
                                              const float* __restrict__ W,
                                              float* __restrict__ feat, int n) {
    __shared__ float hl[32 * K];
    int node0 = blockIdx.x * 32;
    int total4 = 32 * K / 4;
    for (int idx = threadIdx.x; idx < total4; idx += 192) {
        int node = idx / (K / 4);
        int koff = (idx % (K / 4)) * 4;
        float4 v = make_float4(0.f, 0.f, 0.f, 0.f);
        if (node0 + node < n)
            v = *(const float4*)(&h[(size_t)(node0 + node) * K + koff]);
        *(float4*)(&hl[node * K + koff]) = v;
    }
    __syncthreads();
    int grp = threadIdx.x / 48;
    int c = (threadIdx.x % 48) * 2;
    int nb = grp * 8;
    float acc[8][2];
#pragma unroll
    for (int i = 0; i < 8; ++i) acc[i][0] = acc[i][1] = 0.f;
    for (int k = 0; k < K; k += 4) {
        float2 w0 = *(const float2*)&W[(k + 0) * 96 + c];
        float2 w1 = *(const float2*)&W[(k + 1) * 96 + c];
        float2 w2 = *(const float2*)&W[(k + 2) * 96 + c];
        float2 w3 = *(const float2*)&W[(k + 3) * 96 + c];
#pragma unroll
        for (int i = 0; i < 8; ++i) {
            float4 hv = *(const float4*)&hl[(nb + i) * K + k];
            acc[i][0] = fmaf(hv.x, w0.x, acc[i][0]);
            acc[i][1] = fmaf(hv.x, w0.y, acc[i][1]);
            acc[i][0] = fmaf(hv.y, w1.x, acc[i][0]);
            acc[i][1] = fmaf(hv.y, w1.y, acc[i][1]);
            acc[i][0] = fmaf(hv.z, w2.x, acc[i][0]);
            acc[i][1] = fmaf(hv.z, w2.y, acc[i][1]);
            acc[i][0] = fmaf(hv.w, w3.x, acc[i][0]);
            acc[i][1] = fmaf(hv.w, w3.y, acc[i][1]);
        }
    }
#pragma unroll
    for (int i = 0; i < 8; ++i) {
        int node = node0 + nb + i;
        if (node < n) *(float2*)&feat[(size_t)node * 96 + c] = make_float2(acc[i][0], acc[i][1]);
    }
}

// el/er[N,4] = sum_d feat[n,h,d] * a_{l/r}[h,d]
__global__ void k_elr(const float* __restrict__ feat, const float* __restrict__ al,
                      const float* __restrict__ ar, float* __restrict__ el,
                      float* __restrict__ er, int n) {
    int idx = blockIdx.x * blockDim.x + threadIdx.x; // node*4 + h
    if (idx >= n * 4) return;
    int node = idx >> 2, h = idx & 3;
    const float* f = &feat[(size_t)node * 96 + h * 24];
    const float* alh = &al[h * 24];
    const float* arh = &ar[h * 24];
    float sl = 0.f, sr = 0.f;
#pragma unroll
    for (int d4 = 0; d4 < 6; ++d4) {
        float4 v = *(const float4*)&f[d4 * 4];
        float4 a = *(const float4*)&alh[d4 * 4];
        float4 b = *(const float4*)&arh[d4 * 4];
        sl = fmaf(v.x, a.x, sl); sl = fmaf(v.y, a.y, sl);
        sl = fmaf(v.z, a.z, sl); sl = fmaf(v.w, a.w, sl);
        sr = fmaf(v.x, b.x, sr); sr = fmaf(v.y, b.y, sr);
        sr = fmaf(v.z, b.z, sr); sr = fmaf(v.w, b.w, sr);
    }
    el[idx] = sl;
    er[idx] = sr;
}

// per-node: softmax over incoming edges (logits computed on the fly) + aggregation
__global__ __launch_bounds__(128) void k_agg(const int* __restrict__ off,
                                             const int* __restrict__ ssrc,
                                             const float* __restrict__ el,
                                             const float* __restrict__ er,
                                             const float* __restrict__ feat,
                                             const float* __restrict__ bias,
                                             float* __restrict__ out) {
    int n = blockIdx.x;
    int start = off[n], end = off[n + 1];
    int deg = end - start;
    int tid = threadIdx.x;
    int h4 = tid & 3;
    __shared__ float ex_lds[DEG_CAP * 4];
    __shared__ int slds[DEG_CAP];
    __shared__ float mhead[4], rden[4];
    __shared__ float wred[2][4];
    float er_h = er[n * 4 + h4];

    float lm = -1e30f;
    if (deg <= DEG_CAP) {
        // pass 1: e -> LDS, running max
        for (int j = tid >> 2; j < deg; j += 32) {
            int s = ssrc[start + j];
            float e = el[s * 4 + h4] + er_h;
            e = (e > 0.f) ? e : NEG_SLOPE * e;
            ex_lds[j * 4 + h4] = e;
            lm = fmaxf(lm, e);
        }
        for (int j = tid; j < deg; j += 128) slds[j] = ssrc[start + j];
        lm = fmaxf(lm, __shfl_xor(lm, 4));
        lm = fmaxf(lm, __shfl_xor(lm, 8));
        lm = fmaxf(lm, __shfl_xor(lm, 16));
        lm = fmaxf(lm, __shfl_xor(lm, 32));
        if ((tid & 63) < 4) wred[tid >> 6][tid & 3] = lm;
        __syncthreads();
        if (tid < 4) mhead[tid] = fmaxf(wred[0][tid], wred[1][tid]);
        __syncthreads();
        float m = mhead[h4];
        // pass 2: exp in place, running sum
        float lsum = 0.f;
        for (int j = tid >> 2; j < deg; j += 32) {
            float ex = expf(ex_lds[j * 4 + h4] - m);
            ex_lds[j * 4 + h4] = ex;
            lsum += ex;
        }
        lsum += __shfl_xor(lsum, 4);
        lsum += __shfl_xor(lsum, 8);
        lsum += __shfl_xor(lsum, 16);
        lsum += __shfl_xor(lsum, 32);
        if ((tid & 63) < 4) wred[tid >> 6][tid & 3] = lsum;
        __syncthreads();
        if (tid < 4) {
            float v = wred[0][tid] + wred[1][tid];
            rden[tid] = (v > 0.f) ? 1.f / v : 0.f;
        }
        __syncthreads();
        // pass 3: accumulate channels (1/denom factored out)
        if (tid < 96) {
            int h = tid / 24;
            float acc = 0.f;
            for (int e = 0; e < deg; ++e)
                acc = fmaf(ex_lds[e * 4 + h], feat[(size_t)slds[e] * 96 + tid], acc);
            float v = acc * rden[h] + bias[tid];
            out[(size_t)n * 96 + tid] = (v > 0.f) ? v : (expf(v) - 1.f);
        }
    } else {
        // fallback (deg > CAP): streaming recompute, chunked accumulate
        for (int j = tid >> 2; j < deg; j += 32) {
            int s = ssrc[start + j];
            float e = el[s * 4 + h4] + er_h;
            e = (e > 0.f) ? e : NEG_SLOPE * e;
            lm = fmaxf(lm, e);
        }
        lm = fmaxf(lm, __shfl_xor(lm, 4));
        lm = fmaxf(lm, __shfl_xor(lm, 8));
        lm = fmaxf(lm, __shfl_xor(lm, 16));
        lm = fmaxf(lm, __shfl_xor(lm, 32));
        if ((tid & 63) < 4) wred[tid >> 6][tid & 3] = lm;
        __syncthreads();
        if (tid < 4) mhead[tid] = fmaxf(wred[0][tid], wred[1][tid]);
        __syncthreads();
        float m = mhead[h4];
        float lsum = 0.f;
        for (int j = tid >> 2; j < deg; j += 32) {
            int s = ssrc[start + j];
            float e = el[s * 4 + h4] + er_h;
            e = (e > 0.f) ? e : NEG_SLOPE * e;
            lsum += expf(e - m);
        }
        lsum += __shfl_xor(lsum, 4);
        lsum += __shfl_xor(lsum, 8);
        lsum += __shfl_xor(lsum, 16);
        lsum += __shfl_xor(lsum, 32);
        if ((tid & 63) < 4) wred[tid >> 6][tid & 3] = lsum;
        __syncthreads();
        if (tid < 4) {
            float v = wred[0][tid] + wred[1][tid];
            rden[tid] = (v > 0.f) ? 1.f / v : 0.f;
        }
        __syncthreads();
        int h = tid / 24;
        float acc = 0.f;
        for (int cb = 0; cb < deg; cb += DEG_CAP) {
            int cn = min(DEG_CAP, deg - cb);
            for (int j = tid >> 2; j < cn; j += 32) {
                int s = ssrc[start + cb + j];
                float e = el[s * 4 + h4] + er_h;
                e = (e > 0.f) ? e : NEG_SLOPE * e;
                ex_lds[j * 4 + h4] = expf(e - m);
            }
            for (int j = tid; j < cn; j += 128) slds[j] = ssrc[start + cb + j];
            __syncthreads();
            if (tid < 96)
                for (int e = 0; e < cn; ++e)
                    acc = fmaf(ex_lds[e * 4 + h], feat[(size_t)slds[e] * 96 + tid], acc);
            __syncthreads();
        }
        if (tid < 96) {
            float v = acc * rden[h] + bias[tid];
            out[(size_t)n * 96 + tid] = (v > 0.f) ? v : (expf(v) - 1.f);
        }
    }
}

// mean pool over nodes -> out[96]
__global__ __launch_bounds__(128) void k_pool(const float* __restrict__ h,
                                              float* __restrict__ out) {
    int tid = threadIdx.x;
    if (tid >= 96) return;
    float a = 0.f;
    for (int nrow = blockIdx.x; nrow < N_NODES; nrow += gridDim.x)
        a += h[(size_t)nrow * 96 + tid];
    atomicAdd(&out[tid], a * (1.0f / N_NODES));
}

// ---------------- launch ----------------

extern "C" void kernel_launch(void* const* d_in, const int* in_sizes, int n_in,
                              void* d_out, int out_size, void* d_ws, size_t ws_size,
                              hipStream_t stream) {
    const float* feats = (const float*)d_in[0];
    const int* src = (const int*)d_in[1];
    const int* dst = (const int*)d_in[2];

    char* p = (char*)d_ws;
    auto alloc = [&](size_t bytes) {
        void* r = (void*)p;
        p += (bytes + 255) & ~(size_t)255;
        return r;
    };
    float* A      = (float*)alloc((size_t)N_NODES * 96 * 4);
    float* B      = (float*)alloc((size_t)N_NODES * 96 * 4);
    float* el     = (float*)alloc((size_t)N_NODES * 4 * 4);
    float* er     = (float*)alloc((size_t)N_NODES * 4 * 4);
    int* degcur   = (int*)alloc((size_t)N_NODES * 2 * 4); // deg | cursor
    int* off      = (int*)alloc((size_t)(N_NODES + 1) * 4);
    int* bsum     = (int*)alloc((size_t)256 * 4);
    int* ssrc     = (int*)alloc((size_t)E_EDGES * 4);
    int* deg = degcur;
    int* cursor = degcur + N_NODES;

    hipMemsetAsync(degcur, 0, (size_t)N_NODES * 2 * 4, stream);
    hipMemsetAsync(d_out, 0, (size_t)out_size * 4, stream);

    const int NB = (N_NODES + 255) / 256;
    k_hist<<<(E_EDGES + 255) / 256, 256, 0, stream>>>(dst, deg);
    k_scan1<<<NB, 256, 0, stream>>>(deg, bsum, N_NODES);
    k_scan2<<<1, 256, 0, stream>>>(bsum, NB);
    k_scan3<<<NB, 256, 0, stream>>>(deg, bsum, off, N_NODES);
    k_fill<<<(E_EDGES + 255) / 256, 256, 0, stream>>>(src, dst, off, cursor, ssrc);

    const float* hin = feats;
    for (int l = 0; l < 3; ++l) {
        const float* W  = (const float*)d_in[3 + 4 * l];
        const float* al = (const float*)d_in[4 + 4 * l];
        const float* ar = (const float*)d_in[5 + 4 * l];
        const float* bb = (const float*)d_in[6 + 4 * l];

        if (l == 0)
            k_gemm<IN_DIM><<<(N_NODES + 31) / 32, 192, 0, stream>>>(hin, W, B, N_NODES);
        else
            k_gemm<HIDDEN><<<(N_NODES + 31) / 32, 192, 0, stream>>>(hin, W, B, N_NODES);

        k_elr<<<(N_NODES * 4 + 255) / 256, 256, 0, stream>>>(B, al, ar, el, er, N_NODES);
        k_agg<<<N_NODES, 128, 0, stream>>>(off, ssrc, el, er, B, bb, A);
        hin = A;
    }

    k_pool<<<256, 128, 0, stream>>>(A, (float*)d_out);
}

// Round 6
// 527.568 us; speedup vs baseline: 1.3537x; 1.0060x over previous
//
#include <hip/hip_runtime.h>
#include <hip/hip_bf16.h>

#define N_NODES 50000
#define E_EDGES 800000
#define IN_DIM  128
#define HIDDEN  96
#define HEADS   4
#define HEAD_DIM 24
#define NEG_SLOPE 0.2f
#define DEG_CAP 256

// ---------------- CSR build ----------------

__global__ void k_hist(const int* __restrict__ dst, int* __restrict__ deg) {
    int e = blockIdx.x * 256 + threadIdx.x;
    if (e < E_EDGES) atomicAdd(&deg[dst[e]], 1);
}

// block sums of deg
__global__ __launch_bounds__(256) void k_scan1(const int* __restrict__ deg,
                                               int* __restrict__ bsum, int n) {
    int i = blockIdx.x * 256 + threadIdx.x;
    int v = (i < n) ? deg[i] : 0;
#pragma unroll
    for (int s = 1; s < 64; s <<= 1) v += __shfl_xor(v, s);
    __shared__ int ws[4];
    if ((threadIdx.x & 63) == 0) ws[threadIdx.x >> 6] = v;
    __syncthreads();
    if (threadIdx.x == 0) bsum[blockIdx.x] = ws[0] + ws[1] + ws[2] + ws[3];
}

// exclusive scan of block sums (nb <= 256), single block
__global__ __launch_bounds__(256) void k_scan2(int* __restrict__ bsum, int nb) {
    int tid = threadIdx.x;
    int v = (tid < nb) ? bsum[tid] : 0;
    int lane = tid & 63, wv = tid >> 6;
    int x = v;
#pragma unroll
    for (int s = 1; s < 64; s <<= 1) {
        int t = __shfl_up(x, s);
        if (lane >= s) x += t;
    }
    __shared__ int wsum[4];
    if (lane == 63) wsum[wv] = x;
    __syncthreads();
    int add = 0;
    for (int w = 0; w < wv; ++w) add += wsum[w];
    x += add;
    if (tid < nb) bsum[tid] = x - v; // exclusive
}

// final offsets
__global__ __launch_bounds__(256) void k_scan3(const int* __restrict__ deg,
                                               const int* __restrict__ bsum,
                                               int* __restrict__ off, int n) {
    int tid = threadIdx.x;
    int i = blockIdx.x * 256 + tid;
    int v = (i < n) ? deg[i] : 0;
    int lane = tid & 63, wv = tid >> 6;
    int x = v;
#pragma unroll
    for (int s = 1; s < 64; s <<= 1) {
        int t = __shfl_up(x, s);
        if (lane >= s) x += t;
    }
    __shared__ int wsum[4];
    if (lane == 63) wsum[wv] = x;
    __syncthreads();
    int add = bsum[blockIdx.x];
    for (int w = 0; w < wv; ++w) add += wsum[w];
    if (i < n) off[i] = x - v + add;
    if (i == n - 1) off[n] = x + add;
}

__global__ void k_fill(const int* __restrict__ src, const int* __restrict__ dst,
                       const int* __restrict__ off, int* __restrict__ cursor,
                       int* __restrict__ ssrc) {
    int e = blockIdx.x * 256 + threadIdx.x;
    if (e < E_EDGES) {
        int d = dst[e];
        int p = off[d] + atomicAdd(&cursor[d], 1);
        ssrc[p] = src[e];
    }
}

// ---------------- per-layer kernels ----------------

// feat[N,96] = h[N,K] @ W[K,96]; 64 nodes/block, 384 thr = 8 groups x 48 ch-pair threads
template <int K>
__global__ __launch_bounds__(384) void k_gemm(const float* __restrict__ h,
                                              const float* __restrict__ W,
                                              float* __restrict__ feat, int n) {
    __shared__ float hl[64 * K];
    int node0 = blockIdx.x * 64;
    int total4 = 64 * K / 4;
    for (int idx = threadIdx.x; idx < total4; idx += 384) {
        int node = idx / (K / 4);
        int koff = (idx % (K / 4)) * 4;
        float4 v = make_float4(0.f, 0.f, 0.f, 0.f);
        if (node0 + node < n)
            v = *(const float4*)(&h[(size_t)(node0 + node) * K + koff]);
        *(float4*)(&hl[node * K + koff]) = v;
    }
    __syncthreads();
    int grp = threadIdx.x / 48;        // 0..7
    int c = (threadIdx.x % 48) * 2;    // channel pair
    int nb = grp * 8;                  // 8 nodes per group
    float acc[8][2];
#pragma unroll
    for (int i = 0; i < 8; ++i) acc[i][0] = acc[i][1] = 0.f;
    for (int k = 0; k < K; k += 4) {
        float2 w0 = *(const float2*)&W[(k + 0) * 96 + c];
        float2 w1 = *(const float2*)&W[(k + 1) * 96 + c];
        float2 w2 = *(const float2*)&W[(k + 2) * 96 + c];
        float2 w3 = *(const float2*)&W[(k + 3) * 96 + c];
#pragma unroll
        for (int i = 0; i < 8; ++i) {
            float4 hv = *(const float4*)&hl[(nb + i) * K + k];
            acc[i][0] = fmaf(hv.x, w0.x, acc[i][0]);
            acc[i][1] = fmaf(hv.x, w0.y, acc[i][1]);
            acc[i][0] = fmaf(hv.y, w1.x, acc[i][0]);
            acc[i][1] = fmaf(hv.y, w1.y, acc[i][1]);
            acc[i][0] = fmaf(hv.z, w2.x, acc[i][0]);
            acc[i][1] = fmaf(hv.z, w2.y, acc[i][1]);
            acc[i][0] = fmaf(hv.w, w3.x, acc[i][0]);
            acc[i][1] = fmaf(hv.w, w3.y, acc[i][1]);
        }
    }
#pragma unroll
    for (int i = 0; i < 8; ++i) {
        int node = node0 + nb + i;
        if (node < n) *(float2*)&feat[(size_t)node * 96 + c] = make_float2(acc[i][0], acc[i][1]);
    }
}

// el/er[N,4] = sum_d feat[n,h,d] * a_{l/r}[h,d]
__global__ void k_elr(const float* __restrict__ feat, const float* __restrict__ al,
                      const float* __restrict__ ar, float* __restrict__ el,
                      float* __restrict__ er, int n) {
    int idx = blockIdx.x * blockDim.x + threadIdx.x; // node*4 + h
    if (idx >= n * 4) return;
    int node = idx >> 2, h = idx & 3;
    const float* f = &feat[(size_t)node * 96 + h * 24];
    const float* alh = &al[h * 24];
    const float* arh = &ar[h * 24];
    float sl = 0.f, sr = 0.f;
#pragma unroll
    for (int d4 = 0; d4 < 6; ++d4) {
        float4 v = *(const float4*)&f[d4 * 4];
        float4 a = *(const float4*)&alh[d4 * 4];
        float4 b = *(const float4*)&arh[d4 * 4];
        sl = fmaf(v.x, a.x, sl); sl = fmaf(v.y, a.y, sl);
        sl = fmaf(v.z, a.z, sl); sl = fmaf(v.w, a.w, sl);
        sr = fmaf(v.x, b.x, sr); sr = fmaf(v.y, b.y, sr);
        sr = fmaf(v.z, b.z, sr); sr = fmaf(v.w, b.w, sr);
    }
    el[idx] = sl;
    er[idx] = sr;
}

// per-node: softmax over incoming edges (logits on the fly) + aggregation
__global__ __launch_bounds__(128) void k_agg(const int* __restrict__ off,
                                             const int* __restrict__ ssrc,
                                             const float* __restrict__ el,
                                             const float* __restrict__ er,
                                             const float* __restrict__ feat,
                                             const float* __restrict__ bias,
                                             float* __restrict__ out) {
    int n = blockIdx.x;
    int start = off[n], end = off[n + 1];
    int deg = end - start;
    int tid = threadIdx.x;
    int h4 = tid & 3;
    __shared__ float ex_lds[DEG_CAP * 4];
    __shared__ int slds[DEG_CAP];
    __shared__ float wredm[2][4], wreds[2][4];
    __shared__ float sred[4][96];
    float er_h = er[n * 4 + h4];

    float lm = -1e30f;
    if (deg <= DEG_CAP) {
        // pass 1: e -> LDS, running max; stage src ids
        for (int j = tid >> 2; j < deg; j += 32) {
            int s = ssrc[start + j];
            float e = el[s * 4 + h4] + er_h;
            e = (e > 0.f) ? e : NEG_SLOPE * e;
            ex_lds[j * 4 + h4] = e;
            lm = fmaxf(lm, e);
        }
        for (int j = tid; j < deg; j += 128) slds[j] = ssrc[start + j];
        lm = fmaxf(lm, __shfl_xor(lm, 4));
        lm = fmaxf(lm, __shfl_xor(lm, 8));
        lm = fmaxf(lm, __shfl_xor(lm, 16));
        lm = fmaxf(lm, __shfl_xor(lm, 32));
        if ((tid & 63) < 4) wredm[tid >> 6][h4] = lm;
        __syncthreads(); // barrier 1
        float m = fmaxf(wredm[0][h4], wredm[1][h4]);
        // pass 2: exp in place, running sum
        float lsum = 0.f;
        for (int j = tid >> 2; j < deg; j += 32) {
            float ex = expf(ex_lds[j * 4 + h4] - m);
            ex_lds[j * 4 + h4] = ex;
            lsum += ex;
        }
        lsum += __shfl_xor(lsum, 4);
        lsum += __shfl_xor(lsum, 8);
        lsum += __shfl_xor(lsum, 16);
        lsum += __shfl_xor(lsum, 32);
        if ((tid & 63) < 4) wreds[tid >> 6][h4] = lsum;
        __syncthreads(); // barrier 2
        // pass 3: 4 edge-subsets x 24 threads, float4 channels
        if (tid < 96) {
            int sub = tid / 24;
            int c4 = (tid % 24) * 4;
            int hh = c4 / 24;
            float4 acc = make_float4(0.f, 0.f, 0.f, 0.f);
            for (int j = sub; j < deg; j += 4) {
                float a = ex_lds[j * 4 + hh];
                float4 f = *(const float4*)&feat[(size_t)slds[j] * 96 + c4];
                acc.x = fmaf(a, f.x, acc.x);
                acc.y = fmaf(a, f.y, acc.y);
                acc.z = fmaf(a, f.z, acc.z);
                acc.w = fmaf(a, f.w, acc.w);
            }
            *(float4*)&sred[sub][c4] = acc;
        }
        __syncthreads(); // barrier 3
        if (tid < 96) {
            int h = tid / 24;
            float den = wreds[0][h] + wreds[1][h];
            float rden = (den > 0.f) ? 1.f / den : 0.f;
            float s = sred[0][tid] + sred[1][tid] + sred[2][tid] + sred[3][tid];
            float v = s * rden + bias[tid];
            out[(size_t)n * 96 + tid] = (v > 0.f) ? v : (expf(v) - 1.f);
        }
    } else {
        // fallback (deg > CAP): streaming recompute, chunked accumulate
        for (int j = tid >> 2; j < deg; j += 32) {
            int s = ssrc[start + j];
            float e = el[s * 4 + h4] + er_h;
            e = (e > 0.f) ? e : NEG_SLOPE * e;
            lm = fmaxf(lm, e);
        }
        lm = fmaxf(lm, __shfl_xor(lm, 4));
        lm = fmaxf(lm, __shfl_xor(lm, 8));
        lm = fmaxf(lm, __shfl_xor(lm, 16));
        lm = fmaxf(lm, __shfl_xor(lm, 32));
        if ((tid & 63) < 4) wredm[tid >> 6][h4] = lm;
        __syncthreads();
        float m = fmaxf(wredm[0][h4], wredm[1][h4]);
        float lsum = 0.f;
        for (int j = tid >> 2; j < deg; j += 32) {
            int s = ssrc[start + j];
            float e = el[s * 4 + h4] + er_h;
            e = (e > 0.f) ? e : NEG_SLOPE * e;
            lsum += expf(e - m);
        }
        lsum += __shfl_xor(lsum, 4);
        lsum += __shfl_xor(lsum, 8);
        lsum += __shfl_xor(lsum, 16);
        lsum += __shfl_xor(lsum, 32);
        if ((tid & 63) < 4) wreds[tid >> 6][h4] = lsum;
        __syncthreads();
        int h = tid / 24;
        float acc = 0.f;
        for (int cb = 0; cb < deg; cb += DEG_CAP) {
            int cn = min(DEG_CAP, deg - cb);
            for (int j = tid >> 2; j < cn; j += 32) {
                int s = ssrc[start + cb + j];
                float e = el[s * 4 + h4] + er_h;
                e = (e > 0.f) ? e : NEG_SLOPE * e;
                ex_lds[j * 4 + h4] = expf(e - m);
            }
            for (int j = tid; j < cn; j += 128) slds[j] = ssrc[start + cb + j];
            __syncthreads();
            if (tid < 96)
                for (int e = 0; e < cn; ++e)
                    acc = fmaf(ex_lds[e * 4 + h], feat[(size_t)slds[e] * 96 + tid], acc);
            __syncthreads();
        }
        if (tid < 96) {
            float d2 = wreds[0][h] + wreds[1][h];
            float rden = (d2 > 0.f) ? 1.f / d2 : 0.f;
            float v = acc * rden + bias[tid];
            out[(size_t)n * 96 + tid] = (v > 0.f) ? v : (expf(v) - 1.f);
        }
    }
}

// mean pool over nodes -> out[96]
__global__ __launch_bounds__(128) void k_pool(const float* __restrict__ h,
                                              float* __restrict__ out) {
    int tid = threadIdx.x;
    if (tid >= 96) return;
    float a = 0.f;
    for (int nrow = blockIdx.x; nrow < N_NODES; nrow += gridDim.x)
        a += h[(size_t)nrow * 96 + tid];
    atomicAdd(&out[tid], a * (1.0f / N_NODES));
}

// ---------------- launch ----------------

extern "C" void kernel_launch(void* const* d_in, const int* in_sizes, int n_in,
                              void* d_out, int out_size, void* d_ws, size_t ws_size,
                              hipStream_t stream) {
    const float* feats = (const float*)d_in[0];
    const int* src = (const int*)d_in[1];
    const int* dst = (const int*)d_in[2];

    char* p = (char*)d_ws;
    auto alloc = [&](size_t bytes) {
        void* r = (void*)p;
        p += (bytes + 255) & ~(size_t)255;
        return r;
    };
    float* A      = (float*)alloc((size_t)N_NODES * 96 * 4);
    float* B      = (float*)alloc((size_t)N_NODES * 96 * 4);
    float* el     = (float*)alloc((size_t)N_NODES * 4 * 4);
    float* er     = (float*)alloc((size_t)N_NODES * 4 * 4);
    int* degcur   = (int*)alloc((size_t)N_NODES * 2 * 4); // deg | cursor
    int* off      = (int*)alloc((size_t)(N_NODES + 1) * 4);
    int* bsum     = (int*)alloc((size_t)256 * 4);
    int* ssrc     = (int*)alloc((size_t)E_EDGES * 4);
    int* deg = degcur;
    int* cursor = degcur + N_NODES;

    hipMemsetAsync(degcur, 0, (size_t)N_NODES * 2 * 4, stream);
    hipMemsetAsync(d_out, 0, (size_t)out_size * 4, stream);

    const int NB = (N_NODES + 255) / 256;
    k_hist<<<(E_EDGES + 255) / 256, 256, 0, stream>>>(dst, deg);
    k_scan1<<<NB, 256, 0, stream>>>(deg, bsum, N_NODES);
    k_scan2<<<1, 256, 0, stream>>>(bsum, NB);
    k_scan3<<<NB, 256, 0, stream>>>(deg, bsum, off, N_NODES);
    k_fill<<<(E_EDGES + 255) / 256, 256, 0, stream>>>(src, dst, off, cursor, ssrc);

    const float* hin = feats;
    for (int l = 0; l < 3; ++l) {
        const float* W  = (const float*)d_in[3 + 4 * l];
        const float* al = (const float*)d_in[4 + 4 * l];
        const float* ar = (const float*)d_in[5 + 4 * l];
        const float* bb = (const float*)d_in[6 + 4 * l];

        if (l == 0)
            k_gemm<IN_DIM><<<(N_NODES + 63) / 64, 384, 0, stream>>>(hin, W, B, N_NODES);
        else
            k_gemm<HIDDEN><<<(N_NODES + 63) / 64, 384, 0, stream>>>(hin, W, B, N_NODES);

        k_elr<<<(N_NODES * 4 + 255) / 256, 256, 0, stream>>>(B, al, ar, el, er, N_NODES);
        k_agg<<<N_NODES, 128, 0, stream>>>(off, ssrc, el, er, B, bb, A);
        hin = A;
    }

    k_pool<<<256, 128, 0, stream>>>(A, (float*)d_out);
}

// Round 7
// 485.855 us; speedup vs baseline: 1.4700x; 1.0859x over previous
//
#include <hip/hip_runtime.h>
#include <hip/hip_bf16.h>

#define N_NODES 50000
#define E_EDGES 800000
#define IN_DIM  128
#define HIDDEN  96
#define HEADS   4
#define HEAD_DIM 24
#define NEG_SLOPE 0.2f

// ---------------- CSR build ----------------

__global__ void k_hist(const int* __restrict__ dst, int* __restrict__ deg) {
    int e = blockIdx.x * 256 + threadIdx.x;
    if (e < E_EDGES) atomicAdd(&deg[dst[e]], 1);
}

// block sums of deg
__global__ __launch_bounds__(256) void k_scan1(const int* __restrict__ deg,
                                               int* __restrict__ bsum, int n) {
    int i = blockIdx.x * 256 + threadIdx.x;
    int v = (i < n) ? deg[i] : 0;
#pragma unroll
    for (int s = 1; s < 64; s <<= 1) v += __shfl_xor(v, s);
    __shared__ int ws[4];
    if ((threadIdx.x & 63) == 0) ws[threadIdx.x >> 6] = v;
    __syncthreads();
    if (threadIdx.x == 0) bsum[blockIdx.x] = ws[0] + ws[1] + ws[2] + ws[3];
}

// exclusive scan of block sums (nb <= 256), single block
__global__ __launch_bounds__(256) void k_scan2(int* __restrict__ bsum, int nb) {
    int tid = threadIdx.x;
    int v = (tid < nb) ? bsum[tid] : 0;
    int lane = tid & 63, wv = tid >> 6;
    int x = v;
#pragma unroll
    for (int s = 1; s < 64; s <<= 1) {
        int t = __shfl_up(x, s);
        if (lane >= s) x += t;
    }
    __shared__ int wsum[4];
    if (lane == 63) wsum[wv] = x;
    __syncthreads();
    int add = 0;
    for (int w = 0; w < wv; ++w) add += wsum[w];
    x += add;
    if (tid < nb) bsum[tid] = x - v; // exclusive
}

// final offsets
__global__ __launch_bounds__(256) void k_scan3(const int* __restrict__ deg,
                                               const int* __restrict__ bsum,
                                               int* __restrict__ off, int n) {
    int tid = threadIdx.x;
    int i = blockIdx.x * 256 + tid;
    int v = (i < n) ? deg[i] : 0;
    int lane = tid & 63, wv = tid >> 6;
    int x = v;
#pragma unroll
    for (int s = 1; s < 64; s <<= 1) {
        int t = __shfl_up(x, s);
        if (lane >= s) x += t;
    }
    __shared__ int wsum[4];
    if (lane == 63) wsum[wv] = x;
    __syncthreads();
    int add = bsum[blockIdx.x];
    for (int w = 0; w < wv; ++w) add += wsum[w];
    if (i < n) off[i] = x - v + add;
    if (i == n - 1) off[n] = x + add;
}

__global__ void k_fill(const int* __restrict__ src, const int* __restrict__ dst,
                       const int* __restrict__ off, int* __restrict__ cursor,
                       int* __restrict__ ssrc) {
    int e = blockIdx.x * 256 + threadIdx.x;
    if (e < E_EDGES) {
        int d = dst[e];
        int p = off[d] + atomicAdd(&cursor[d], 1);
        ssrc[p] = src[e];
    }
}

// ---------------- per-layer kernels ----------------

// feat[N,96] = h[N,K] @ W[K,96]; 64 nodes/block, 384 thr = 8 groups x 48 ch-pair threads
template <int K>
__global__ __launch_bounds__(384) void k_gemm(const float* __restrict__ h,
                                              const float* __restrict__ W,
                                              float* __restrict__ feat, int n) {
    __shared__ float hl[64 * K];
    int node0 = blockIdx.x * 64;
    int total4 = 64 * K / 4;
    for (int idx = threadIdx.x; idx < total4; idx += 384) {
        int node = idx / (K / 4);
        int koff = (idx % (K / 4)) * 4;
        float4 v = make_float4(0.f, 0.f, 0.f, 0.f);
        if (node0 + node < n)
            v = *(const float4*)(&h[(size_t)(node0 + node) * K + koff]);
        *(float4*)(&hl[node * K + koff]) = v;
    }
    __syncthreads();
    int grp = threadIdx.x / 48;        // 0..7
    int c = (threadIdx.x % 48) * 2;    // channel pair
    int nb = grp * 8;                  // 8 nodes per group
    float acc[8][2];
#pragma unroll
    for (int i = 0; i < 8; ++i) acc[i][0] = acc[i][1] = 0.f;
    for (int k = 0; k < K; k += 4) {
        float2 w0 = *(const float2*)&W[(k + 0) * 96 + c];
        float2 w1 = *(const float2*)&W[(k + 1) * 96 + c];
        float2 w2 = *(const float2*)&W[(k + 2) * 96 + c];
        float2 w3 = *(const float2*)&W[(k + 3) * 96 + c];
#pragma unroll
        for (int i = 0; i < 8; ++i) {
            float4 hv = *(const float4*)&hl[(nb + i) * K + k];
            acc[i][0] = fmaf(hv.x, w0.x, acc[i][0]);
            acc[i][1] = fmaf(hv.x, w0.y, acc[i][1]);
            acc[i][0] = fmaf(hv.y, w1.x, acc[i][0]);
            acc[i][1] = fmaf(hv.y, w1.y, acc[i][1]);
            acc[i][0] = fmaf(hv.z, w2.x, acc[i][0]);
            acc[i][1] = fmaf(hv.z, w2.y, acc[i][1]);
            acc[i][0] = fmaf(hv.w, w3.x, acc[i][0]);
            acc[i][1] = fmaf(hv.w, w3.y, acc[i][1]);
        }
    }
#pragma unroll
    for (int i = 0; i < 8; ++i) {
        int node = node0 + nb + i;
        if (node < n) *(float2*)&feat[(size_t)node * 96 + c] = make_float2(acc[i][0], acc[i][1]);
    }
}

// el/er[N,4] = sum_d feat[n,h,d] * a_{l/r}[h,d]
__global__ void k_elr(const float* __restrict__ feat, const float* __restrict__ al,
                      const float* __restrict__ ar, float* __restrict__ el,
                      float* __restrict__ er, int n) {
    int idx = blockIdx.x * blockDim.x + threadIdx.x; // node*4 + h
    if (idx >= n * 4) return;
    int node = idx >> 2, h = idx & 3;
    const float* f = &feat[(size_t)node * 96 + h * 24];
    const float* alh = &al[h * 24];
    const float* arh = &ar[h * 24];
    float sl = 0.f, sr = 0.f;
#pragma unroll
    for (int d4 = 0; d4 < 6; ++d4) {
        float4 v = *(const float4*)&f[d4 * 4];
        float4 a = *(const float4*)&alh[d4 * 4];
        float4 b = *(const float4*)&arh[d4 * 4];
        sl = fmaf(v.x, a.x, sl); sl = fmaf(v.y, a.y, sl);
        sl = fmaf(v.z, a.z, sl); sl = fmaf(v.w, a.w, sl);
        sr = fmaf(v.x, b.x, sr); sr = fmaf(v.y, b.y, sr);
        sr = fmaf(v.z, b.z, sr); sr = fmaf(v.w, b.w, sr);
    }
    el[idx] = sl;
    er[idx] = sr;
}

// per-node edge-softmax + aggregation: ONE WAVE PER NODE, no LDS, no barriers.
// lane = j0*8 + h*2 + half;  j0 = edge slot (8 per tile), h = head,
// half selects channels [h*24 + half*12, +12).  The alpha a lane computes in
// the softmax phase is exactly the alpha it needs in the PV phase.
__global__ __launch_bounds__(256) void k_agg(const int* __restrict__ off,
                                             const int* __restrict__ ssrc,
                                             const float* __restrict__ el,
                                             const float* __restrict__ er,
                                             const float* __restrict__ feat,
                                             const float* __restrict__ bias,
                                             float* __restrict__ out) {
    int n = blockIdx.x * 4 + (threadIdx.x >> 6);
    if (n >= N_NODES) return;
    int lane = threadIdx.x & 63;
    int j0   = lane >> 3;        // 0..7
    int h    = (lane >> 1) & 3;  // head
    int half = lane & 1;         // half of head's 24 channels
    int cbase = h * 24 + half * 12;

    int start = off[n], deg = off[n + 1] - start;
    float er_h = er[n * 4 + h];

    // ---- pass A: gather e into regs (up to 32 edges), running max
    float e_reg[4];
    int   s_reg[4];
    float lmax = -1e30f;
#pragma unroll
    for (int t = 0; t < 4; ++t) {
        int j = t * 8 + j0;
        bool act = (j < deg);
        int s = act ? ssrc[start + j] : 0;
        float e = -1e30f;
        if (act) {
            e = el[s * 4 + h] + er_h;
            e = (e > 0.f) ? e : NEG_SLOPE * e;
        }
        s_reg[t] = s;
        e_reg[t] = e;
        lmax = fmaxf(lmax, e);
    }
    // rare deg > 32: streamed max
    for (int j = 32 + j0; j < deg; j += 8) {
        int s = ssrc[start + j];
        float e = el[s * 4 + h] + er_h;
        e = (e > 0.f) ? e : NEG_SLOPE * e;
        lmax = fmaxf(lmax, e);
    }
    lmax = fmaxf(lmax, __shfl_xor(lmax, 8));
    lmax = fmaxf(lmax, __shfl_xor(lmax, 16));
    lmax = fmaxf(lmax, __shfl_xor(lmax, 32));
    float m = lmax;

    // ---- pass B: fused exp + denom + 12-channel accumulate
    float acc[12];
#pragma unroll
    for (int c = 0; c < 12; ++c) acc[c] = 0.f;
    float den = 0.f;
#pragma unroll
    for (int t = 0; t < 4; ++t) {
        int j = t * 8 + j0;
        if (j < deg) {
            float ex = expf(e_reg[t] - m);
            den += ex;
            const float* fr = &feat[(size_t)s_reg[t] * 96 + cbase];
            float4 v0 = *(const float4*)(fr + 0);
            float4 v1 = *(const float4*)(fr + 4);
            float4 v2 = *(const float4*)(fr + 8);
            acc[0] = fmaf(ex, v0.x, acc[0]);  acc[1] = fmaf(ex, v0.y, acc[1]);
            acc[2] = fmaf(ex, v0.z, acc[2]);  acc[3] = fmaf(ex, v0.w, acc[3]);
            acc[4] = fmaf(ex, v1.x, acc[4]);  acc[5] = fmaf(ex, v1.y, acc[5]);
            acc[6] = fmaf(ex, v1.z, acc[6]);  acc[7] = fmaf(ex, v1.w, acc[7]);
            acc[8] = fmaf(ex, v2.x, acc[8]);  acc[9] = fmaf(ex, v2.y, acc[9]);
            acc[10] = fmaf(ex, v2.z, acc[10]); acc[11] = fmaf(ex, v2.w, acc[11]);
        }
    }
    for (int j = 32 + j0; j < deg; j += 8) {
        int s = ssrc[start + j];
        float e = el[s * 4 + h] + er_h;
        e = (e > 0.f) ? e : NEG_SLOPE * e;
        float ex = expf(e - m);
        den += ex;
        const float* fr = &feat[(size_t)s * 96 + cbase];
        float4 v0 = *(const float4*)(fr + 0);
        float4 v1 = *(const float4*)(fr + 4);
        float4 v2 = *(const float4*)(fr + 8);
        acc[0] = fmaf(ex, v0.x, acc[0]);  acc[1] = fmaf(ex, v0.y, acc[1]);
        acc[2] = fmaf(ex, v0.z, acc[2]);  acc[3] = fmaf(ex, v0.w, acc[3]);
        acc[4] = fmaf(ex, v1.x, acc[4]);  acc[5] = fmaf(ex, v1.y, acc[5]);
        acc[6] = fmaf(ex, v1.z, acc[6]);  acc[7] = fmaf(ex, v1.w, acc[7]);
        acc[8] = fmaf(ex, v2.x, acc[8]);  acc[9] = fmaf(ex, v2.y, acc[9]);
        acc[10] = fmaf(ex, v2.z, acc[10]); acc[11] = fmaf(ex, v2.w, acc[11]);
    }

    // ---- butterfly reduce over the 8 j-lanes (bits 3,4,5): 13 values
#pragma unroll
    for (int st = 8; st <= 32; st <<= 1) {
        den += __shfl_xor(den, st);
#pragma unroll
        for (int c = 0; c < 12; ++c) acc[c] += __shfl_xor(acc[c], st);
    }

    // ---- epilogue: lanes with j0==0 write their 12 channels
    if (j0 == 0) {
        float rden = (den > 0.f) ? 1.f / den : 0.f;
        const float* bp = &bias[cbase];
        float o[12];
#pragma unroll
        for (int c = 0; c < 12; ++c) {
            float v = acc[c] * rden + bp[c];
            o[c] = (v > 0.f) ? v : (expf(v) - 1.f);
        }
        float* op = &out[(size_t)n * 96 + cbase];
        *(float4*)(op + 0) = make_float4(o[0], o[1], o[2], o[3]);
        *(float4*)(op + 4) = make_float4(o[4], o[5], o[6], o[7]);
        *(float4*)(op + 8) = make_float4(o[8], o[9], o[10], o[11]);
    }
}

// mean pool over nodes -> out[96]
__global__ __launch_bounds__(128) void k_pool(const float* __restrict__ h,
                                              float* __restrict__ out) {
    int tid = threadIdx.x;
    if (tid >= 96) return;
    float a = 0.f;
    for (int nrow = blockIdx.x; nrow < N_NODES; nrow += gridDim.x)
        a += h[(size_t)nrow * 96 + tid];
    atomicAdd(&out[tid], a * (1.0f / N_NODES));
}

// ---------------- launch ----------------

extern "C" void kernel_launch(void* const* d_in, const int* in_sizes, int n_in,
                              void* d_out, int out_size, void* d_ws, size_t ws_size,
                              hipStream_t stream) {
    const float* feats = (const float*)d_in[0];
    const int* src = (const int*)d_in[1];
    const int* dst = (const int*)d_in[2];

    char* p = (char*)d_ws;
    auto alloc = [&](size_t bytes) {
        void* r = (void*)p;
        p += (bytes + 255) & ~(size_t)255;
        return r;
    };
    float* A      = (float*)alloc((size_t)N_NODES * 96 * 4);
    float* B      = (float*)alloc((size_t)N_NODES * 96 * 4);
    float* el     = (float*)alloc((size_t)N_NODES * 4 * 4);
    float* er     = (float*)alloc((size_t)N_NODES * 4 * 4);
    int* degcur   = (int*)alloc((size_t)N_NODES * 2 * 4); // deg | cursor
    int* off      = (int*)alloc((size_t)(N_NODES + 1) * 4);
    int* bsum     = (int*)alloc((size_t)256 * 4);
    int* ssrc     = (int*)alloc((size_t)E_EDGES * 4);
    int* deg = degcur;
    int* cursor = degcur + N_NODES;

    hipMemsetAsync(degcur, 0, (size_t)N_NODES * 2 * 4, stream);
    hipMemsetAsync(d_out, 0, (size_t)out_size * 4, stream);

    const int NB = (N_NODES + 255) / 256;
    k_hist<<<(E_EDGES + 255) / 256, 256, 0, stream>>>(dst, deg);
    k_scan1<<<NB, 256, 0, stream>>>(deg, bsum, N_NODES);
    k_scan2<<<1, 256, 0, stream>>>(bsum, NB);
    k_scan3<<<NB, 256, 0, stream>>>(deg, bsum, off, N_NODES);
    k_fill<<<(E_EDGES + 255) / 256, 256, 0, stream>>>(src, dst, off, cursor, ssrc);

    const float* hin = feats;
    for (int l = 0; l < 3; ++l) {
        const float* W  = (const float*)d_in[3 + 4 * l];
        const float* al = (const float*)d_in[4 + 4 * l];
        const float* ar = (const float*)d_in[5 + 4 * l];
        const float* bb = (const float*)d_in[6 + 4 * l];

        if (l == 0)
            k_gemm<IN_DIM><<<(N_NODES + 63) / 64, 384, 0, stream>>>(hin, W, B, N_NODES);
        else
            k_gemm<HIDDEN><<<(N_NODES + 63) / 64, 384, 0, stream>>>(hin, W, B, N_NODES);

        k_elr<<<(N_NODES * 4 + 255) / 256, 256, 0, stream>>>(B, al, ar, el, er, N_NODES);
        k_agg<<<(N_NODES + 3) / 4, 256, 0, stream>>>(off, ssrc, el, er, B, bb, A);
        hin = A;
    }

    k_pool<<<256, 128, 0, stream>>>(A, (float*)d_out);
}

// Round 9
// 440.048 us; speedup vs baseline: 1.6230x; 1.1041x over previous
//
#include <hip/hip_runtime.h>
#include <hip/hip_bf16.h>

#define N_NODES 50000
#define E_EDGES 800000
#define IN_DIM  128
#define HIDDEN  96
#define HEADS   4
#define HEAD_DIM 24
#define NEG_SLOPE 0.2f
#define POOL_BLOCKS 256

// ---------------- CSR build ----------------

__global__ void k_hist(const int* __restrict__ dst, int* __restrict__ deg) {
    int e = blockIdx.x * 256 + threadIdx.x;
    if (e < E_EDGES) atomicAdd(&deg[dst[e]], 1);
}

// block sums of deg
__global__ __launch_bounds__(256) void k_scan1(const int* __restrict__ deg,
                                               int* __restrict__ bsum, int n) {
    int i = blockIdx.x * 256 + threadIdx.x;
    int v = (i < n) ? deg[i] : 0;
#pragma unroll
    for (int s = 1; s < 64; s <<= 1) v += __shfl_xor(v, s);
    __shared__ int ws[4];
    if ((threadIdx.x & 63) == 0) ws[threadIdx.x >> 6] = v;
    __syncthreads();
    if (threadIdx.x == 0) bsum[blockIdx.x] = ws[0] + ws[1] + ws[2] + ws[3];
}

// exclusive scan of block sums (nb <= 256), single block
__global__ __launch_bounds__(256) void k_scan2(int* __restrict__ bsum, int nb) {
    int tid = threadIdx.x;
    int v = (tid < nb) ? bsum[tid] : 0;
    int lane = tid & 63, wv = tid >> 6;
    int x = v;
#pragma unroll
    for (int s = 1; s < 64; s <<= 1) {
        int t = __shfl_up(x, s);
        if (lane >= s) x += t;
    }
    __shared__ int wsum[4];
    if (lane == 63) wsum[wv] = x;
    __syncthreads();
    int add = 0;
    for (int w = 0; w < wv; ++w) add += wsum[w];
    x += add;
    if (tid < nb) bsum[tid] = x - v; // exclusive
}

// final offsets
__global__ __launch_bounds__(256) void k_scan3(const int* __restrict__ deg,
                                               const int* __restrict__ bsum,
                                               int* __restrict__ off, int n) {
    int tid = threadIdx.x;
    int i = blockIdx.x * 256 + tid;
    int v = (i < n) ? deg[i] : 0;
    int lane = tid & 63, wv = tid >> 6;
    int x = v;
#pragma unroll
    for (int s = 1; s < 64; s <<= 1) {
        int t = __shfl_up(x, s);
        if (lane >= s) x += t;
    }
    __shared__ int wsum[4];
    if (lane == 63) wsum[wv] = x;
    __syncthreads();
    int add = bsum[blockIdx.x];
    for (int w = 0; w < wv; ++w) add += wsum[w];
    if (i < n) off[i] = x - v + add;
    if (i == n - 1) off[n] = x + add;
}

__global__ void k_fill(const int* __restrict__ src, const int* __restrict__ dst,
                       const int* __restrict__ off, int* __restrict__ cursor,
                       int* __restrict__ ssrc) {
    int e = blockIdx.x * 256 + threadIdx.x;
    if (e < E_EDGES) {
        int d = dst[e];
        int p = off[d] + atomicAdd(&cursor[d], 1);
        ssrc[p] = src[e];
    }
}

// ---------------- per-layer kernels ----------------

// feat[N,96] = h[N,K] @ W[K,96] + fused el/er computation.
// 64 nodes/block, 384 thr = 8 node-groups x 48 channel-pair threads.
// After the GEMM main loop the hl LDS buffer is reused (post-barrier) as a
// 384x17-padded staging area for the per-(node,head) el/er tree reduction.
template <int K>
__global__ __launch_bounds__(384) void k_gemm(const float* __restrict__ h,
                                              const float* __restrict__ W,
                                              const float* __restrict__ al_g,
                                              const float* __restrict__ ar_g,
                                              float* __restrict__ feat,
                                              float* __restrict__ el,
                                              float* __restrict__ er, int n) {
    constexpr int HL = 64 * K;
    constexpr int PT = 384 * 17;
    constexpr int SM = (HL > PT) ? HL : PT;
    __shared__ float smem[SM];
    float* hl = smem;

    int node0 = blockIdx.x * 64;
    int total4 = 64 * K / 4;
    for (int idx = threadIdx.x; idx < total4; idx += 384) {
        int node = idx / (K / 4);
        int koff = (idx % (K / 4)) * 4;
        float4 v = make_float4(0.f, 0.f, 0.f, 0.f);
        if (node0 + node < n)
            v = *(const float4*)(&h[(size_t)(node0 + node) * K + koff]);
        *(float4*)(&hl[node * K + koff]) = v;
    }
    __syncthreads();
    int grp = threadIdx.x / 48;        // 0..7
    int c = (threadIdx.x % 48) * 2;    // channel pair
    int nb = grp * 8;                  // 8 nodes per group
    float acc[8][2];
#pragma unroll
    for (int i = 0; i < 8; ++i) acc[i][0] = acc[i][1] = 0.f;
    for (int k = 0; k < K; k += 4) {
        float2 w0 = *(const float2*)&W[(k + 0) * 96 + c];
        float2 w1 = *(const float2*)&W[(k + 1) * 96 + c];
        float2 w2 = *(const float2*)&W[(k + 2) * 96 + c];
        float2 w3 = *(const float2*)&W[(k + 3) * 96 + c];
#pragma unroll
        for (int i = 0; i < 8; ++i) {
            float4 hv = *(const float4*)&hl[(nb + i) * K + k];
            acc[i][0] = fmaf(hv.x, w0.x, acc[i][0]);
            acc[i][1] = fmaf(hv.x, w0.y, acc[i][1]);
            acc[i][0] = fmaf(hv.y, w1.x, acc[i][0]);
            acc[i][1] = fmaf(hv.y, w1.y, acc[i][1]);
            acc[i][0] = fmaf(hv.z, w2.x, acc[i][0]);
            acc[i][1] = fmaf(hv.z, w2.y, acc[i][1]);
            acc[i][0] = fmaf(hv.w, w3.x, acc[i][0]);
            acc[i][1] = fmaf(hv.w, w3.y, acc[i][1]);
        }
    }
    // feat store (register-only, before LDS reuse barrier)
#pragma unroll
    for (int i = 0; i < 8; ++i) {
        int node = node0 + nb + i;
        if (node < n) *(float2*)&feat[(size_t)node * 96 + c] = make_float2(acc[i][0], acc[i][1]);
    }
    // el/er partials into reused LDS (pad 17 to spread banks)
    float alc0 = al_g[c], alc1 = al_g[c + 1];
    float arc0 = ar_g[c], arc1 = ar_g[c + 1];
    __syncthreads(); // all hl reads done; safe to reuse
    float* part = smem;
    int base = threadIdx.x * 17;
#pragma unroll
    for (int i = 0; i < 8; ++i) {
        part[base + i * 2]     = acc[i][0] * alc0 + acc[i][1] * alc1;
        part[base + i * 2 + 1] = acc[i][0] * arc0 + acc[i][1] * arc1;
    }
    __syncthreads();
    if (threadIdx.x < 256) {
        int ig = threadIdx.x >> 2;      // node in block (0..63)
        int hh = threadIdx.x & 3;       // head
        int g2 = ig >> 3, il = ig & 7;  // group, node-in-group
        float se = 0.f, sr = 0.f;
#pragma unroll
        for (int cc = 0; cc < 12; ++cc) {
            int t = g2 * 48 + hh * 12 + cc;
            se += part[t * 17 + il * 2];
            sr += part[t * 17 + il * 2 + 1];
        }
        int node = node0 + ig;
        if (node < n) {
            el[node * 4 + hh] = se;
            er[node * 4 + hh] = sr;
        }
    }
}

// per-node edge-softmax + aggregation: ONE WAVE PER NODE, no LDS, no barriers.
// lane = j0*8 + h*2 + half;  j0 = edge slot (8 per tile), h = head,
// half selects channels [h*24 + half*12, +12).
__global__ __launch_bounds__(256) void k_agg(const int* __restrict__ off,
                                             const int* __restrict__ ssrc,
                                             const float* __restrict__ el,
                                             const float* __restrict__ er,
                                             const float* __restrict__ feat,
                                             const float* __restrict__ bias,
                                             float* __restrict__ out) {
    int n = blockIdx.x * 4 + (threadIdx.x >> 6);
    if (n >= N_NODES) return;
    int lane = threadIdx.x & 63;
    int j0   = lane >> 3;        // 0..7
    int h    = (lane >> 1) & 3;  // head
    int half = lane & 1;         // half of head's 24 channels
    int cbase = h * 24 + half * 12;

    int start = off[n], deg = off[n + 1] - start;
    float er_h = er[n * 4 + h];

    // ---- pass A: gather e into regs (up to 32 edges), running max
    float e_reg[4];
    int   s_reg[4];
    float lmax = -1e30f;
#pragma unroll
    for (int t = 0; t < 4; ++t) {
        int j = t * 8 + j0;
        bool act = (j < deg);
        int s = act ? ssrc[start + j] : 0;
        float e = -1e30f;
        if (act) {
            e = el[s * 4 + h] + er_h;
            e = (e > 0.f) ? e : NEG_SLOPE * e;
        }
        s_reg[t] = s;
        e_reg[t] = e;
        lmax = fmaxf(lmax, e);
    }
    for (int j = 32 + j0; j < deg; j += 8) {
        int s = ssrc[start + j];
        float e = el[s * 4 + h] + er_h;
        e = (e > 0.f) ? e : NEG_SLOPE * e;
        lmax = fmaxf(lmax, e);
    }
    lmax = fmaxf(lmax, __shfl_xor(lmax, 8));
    lmax = fmaxf(lmax, __shfl_xor(lmax, 16));
    lmax = fmaxf(lmax, __shfl_xor(lmax, 32));
    float m = lmax;

    // ---- pass B: fused exp + denom + 12-channel accumulate
    float acc[12];
#pragma unroll
    for (int c = 0; c < 12; ++c) acc[c] = 0.f;
    float den = 0.f;
#pragma unroll
    for (int t = 0; t < 4; ++t) {
        int j = t * 8 + j0;
        if (j < deg) {
            float ex = expf(e_reg[t] - m);
            den += ex;
            const float* fr = &feat[(size_t)s_reg[t] * 96 + cbase];
            float4 v0 = *(const float4*)(fr + 0);
            float4 v1 = *(const float4*)(fr + 4);
            float4 v2 = *(const float4*)(fr + 8);
            acc[0] = fmaf(ex, v0.x, acc[0]);  acc[1] = fmaf(ex, v0.y, acc[1]);
            acc[2] = fmaf(ex, v0.z, acc[2]);  acc[3] = fmaf(ex, v0.w, acc[3]);
            acc[4] = fmaf(ex, v1.x, acc[4]);  acc[5] = fmaf(ex, v1.y, acc[5]);
            acc[6] = fmaf(ex, v1.z, acc[6]);  acc[7] = fmaf(ex, v1.w, acc[7]);
            acc[8] = fmaf(ex, v2.x, acc[8]);  acc[9] = fmaf(ex, v2.y, acc[9]);
            acc[10] = fmaf(ex, v2.z, acc[10]); acc[11] = fmaf(ex, v2.w, acc[11]);
        }
    }
    for (int j = 32 + j0; j < deg; j += 8) {
        int s = ssrc[start + j];
        float e = el[s * 4 + h] + er_h;
        e = (e > 0.f) ? e : NEG_SLOPE * e;
        float ex = expf(e - m);
        den += ex;
        const float* fr = &feat[(size_t)s * 96 + cbase];
        float4 v0 = *(const float4*)(fr + 0);
        float4 v1 = *(const float4*)(fr + 4);
        float4 v2 = *(const float4*)(fr + 8);
        acc[0] = fmaf(ex, v0.x, acc[0]);  acc[1] = fmaf(ex, v0.y, acc[1]);
        acc[2] = fmaf(ex, v0.z, acc[2]);  acc[3] = fmaf(ex, v0.w, acc[3]);
        acc[4] = fmaf(ex, v1.x, acc[4]);  acc[5] = fmaf(ex, v1.y, acc[5]);
        acc[6] = fmaf(ex, v1.z, acc[6]);  acc[7] = fmaf(ex, v1.w, acc[7]);
        acc[8] = fmaf(ex, v2.x, acc[8]);  acc[9] = fmaf(ex, v2.y, acc[9]);
        acc[10] = fmaf(ex, v2.z, acc[10]); acc[11] = fmaf(ex, v2.w, acc[11]);
    }

    // ---- butterfly reduce over the 8 j-lanes (bits 3,4,5): 13 values
#pragma unroll
    for (int st = 8; st <= 32; st <<= 1) {
        den += __shfl_xor(den, st);
#pragma unroll
        for (int c = 0; c < 12; ++c) acc[c] += __shfl_xor(acc[c], st);
    }

    // ---- epilogue: lanes with j0==0 write their 12 channels
    if (j0 == 0) {
        float rden = (den > 0.f) ? 1.f / den : 0.f;
        const float* bp = &bias[cbase];
        float o[12];
#pragma unroll
        for (int c = 0; c < 12; ++c) {
            float v = acc[c] * rden + bp[c];
            o[c] = (v > 0.f) ? v : (expf(v) - 1.f);
        }
        float* op = &out[(size_t)n * 96 + cbase];
        *(float4*)(op + 0) = make_float4(o[0], o[1], o[2], o[3]);
        *(float4*)(op + 4) = make_float4(o[4], o[5], o[6], o[7]);
        *(float4*)(op + 8) = make_float4(o[8], o[9], o[10], o[11]);
    }
}

// mean pool stage 1: block-partials, 4 rows x 96 channels per block
__global__ __launch_bounds__(384) void k_pool1(const float* __restrict__ h,
                                               float* __restrict__ partial) {
    int r = threadIdx.x / 96;   // 0..3
    int c = threadIdx.x % 96;
    float a = 0.f;
    for (int nrow = blockIdx.x * 4 + r; nrow < N_NODES; nrow += POOL_BLOCKS * 4)
        a += h[(size_t)nrow * 96 + c];
    __shared__ float sred[4][96];
    sred[r][c] = a;
    __syncthreads();
    if (r == 0)
        partial[blockIdx.x * 96 + c] = sred[0][c] + sred[1][c] + sred[2][c] + sred[3][c];
}

// mean pool stage 2: reduce partials, write out directly
__global__ __launch_bounds__(384) void k_pool2(const float* __restrict__ partial,
                                               float* __restrict__ out) {
    int g = threadIdx.x / 96;   // 0..3
    int c = threadIdx.x % 96;
    float a = 0.f;
    for (int b = g; b < POOL_BLOCKS; b += 4)
        a += partial[b * 96 + c];
    __shared__ float sred[4][96];
    sred[g][c] = a;
    __syncthreads();
    if (g == 0)
        out[c] = (sred[0][c] + sred[1][c] + sred[2][c] + sred[3][c]) * (1.0f / N_NODES);
}

// ---------------- launch ----------------

extern "C" void kernel_launch(void* const* d_in, const int* in_sizes, int n_in,
                              void* d_out, int out_size, void* d_ws, size_t ws_size,
                              hipStream_t stream) {
    const float* feats = (const float*)d_in[0];
    const int* src = (const int*)d_in[1];
    const int* dst = (const int*)d_in[2];

    char* p = (char*)d_ws;
    auto alloc = [&](size_t bytes) {
        void* r = (void*)p;
        p += (bytes + 255) & ~(size_t)255;
        return r;
    };
    float* A       = (float*)alloc((size_t)N_NODES * 96 * 4);
    float* B       = (float*)alloc((size_t)N_NODES * 96 * 4);
    float* el      = (float*)alloc((size_t)N_NODES * 4 * 4);
    float* er      = (float*)alloc((size_t)N_NODES * 4 * 4);
    int* degcur    = (int*)alloc((size_t)N_NODES * 2 * 4); // deg | cursor
    int* off       = (int*)alloc((size_t)(N_NODES + 1) * 4);
    int* bsum      = (int*)alloc((size_t)256 * 4);
    int* ssrc      = (int*)alloc((size_t)E_EDGES * 4);
    float* partial = (float*)alloc((size_t)POOL_BLOCKS * 96 * 4);
    int* deg = degcur;
    int* cursor = degcur + N_NODES;

    hipMemsetAsync(degcur, 0, (size_t)N_NODES * 2 * 4, stream);

    const int NB = (N_NODES + 255) / 256;
    k_hist<<<(E_EDGES + 255) / 256, 256, 0, stream>>>(dst, deg);
    k_scan1<<<NB, 256, 0, stream>>>(deg, bsum, N_NODES);
    k_scan2<<<1, 256, 0, stream>>>(bsum, NB);
    k_scan3<<<NB, 256, 0, stream>>>(deg, bsum, off, N_NODES);
    k_fill<<<(E_EDGES + 255) / 256, 256, 0, stream>>>(src, dst, off, cursor, ssrc);

    const float* hin = feats;
    for (int l = 0; l < 3; ++l) {
        const float* W  = (const float*)d_in[3 + 4 * l];
        const float* al = (const float*)d_in[4 + 4 * l];
        const float* ar = (const float*)d_in[5 + 4 * l];
        const float* bb = (const float*)d_in[6 + 4 * l];

        if (l == 0)
            k_gemm<IN_DIM><<<(N_NODES + 63) / 64, 384, 0, stream>>>(hin, W, al, ar, B, el, er, N_NODES);
        else
            k_gemm<HIDDEN><<<(N_NODES + 63) / 64, 384, 0, stream>>>(hin, W, al, ar, B, el, er, N_NODES);

        k_agg<<<(N_NODES + 3) / 4, 256, 0, stream>>>(off, ssrc, el, er, B, bb, A);
        hin = A;
    }

    k_pool1<<<POOL_BLOCKS, 384, 0, stream>>>(A, partial);
    k_pool2<<<1, 384, 0, stream>>>(partial, (float*)d_out);
}

// Round 10
// 439.521 us; speedup vs baseline: 1.6249x; 1.0012x over previous
//
#include <hip/hip_runtime.h>
#include <hip/hip_bf16.h>

#define N_NODES 50000
#define E_EDGES 800000
#define IN_DIM  128
#define HIDDEN  96
#define HEADS   4
#define HEAD_DIM 24
#define NEG_SLOPE 0.2f
#define POOL_BLOCKS 256

// ---------------- CSR build ----------------

__global__ void k_hist(const int* __restrict__ dst, int* __restrict__ deg) {
    int e = blockIdx.x * 256 + threadIdx.x;
    if (e < E_EDGES) atomicAdd(&deg[dst[e]], 1);
}

// block sums of deg
__global__ __launch_bounds__(256) void k_scan1(const int* __restrict__ deg,
                                               int* __restrict__ bsum, int n) {
    int i = blockIdx.x * 256 + threadIdx.x;
    int v = (i < n) ? deg[i] : 0;
#pragma unroll
    for (int s = 1; s < 64; s <<= 1) v += __shfl_xor(v, s);
    __shared__ int ws[4];
    if ((threadIdx.x & 63) == 0) ws[threadIdx.x >> 6] = v;
    __syncthreads();
    if (threadIdx.x == 0) bsum[blockIdx.x] = ws[0] + ws[1] + ws[2] + ws[3];
}

// offsets: each block reduces bsum[0..blockIdx) itself (nb <= 256) + local scan
__global__ __launch_bounds__(256) void k_scan3(const int* __restrict__ deg,
                                               const int* __restrict__ bsum,
                                               int* __restrict__ off, int n) {
    int tid = threadIdx.x;
    int lane = tid & 63, wv = tid >> 6;

    // partial for block-offset reduction
    int pv = (tid < blockIdx.x) ? bsum[tid] : 0;
#pragma unroll
    for (int s = 1; s < 64; s <<= 1) pv += __shfl_xor(pv, s);

    // local scan of this block's 256 degs
    int i = blockIdx.x * 256 + tid;
    int v = (i < n) ? deg[i] : 0;
    int x = v;
#pragma unroll
    for (int s = 1; s < 64; s <<= 1) {
        int t = __shfl_up(x, s);
        if (lane >= s) x += t;
    }

    __shared__ int wsum[4], wsum2[4];
    if (lane == 63) wsum[wv] = x;
    if (lane == 0)  wsum2[wv] = pv;
    __syncthreads();
    int add = wsum2[0] + wsum2[1] + wsum2[2] + wsum2[3];
    for (int w = 0; w < wv; ++w) add += wsum[w];
    if (i < n) off[i] = x - v + add;
    if (i == n - 1) off[n] = x + add;
}

__global__ void k_fill(const int* __restrict__ src, const int* __restrict__ dst,
                       const int* __restrict__ off, int* __restrict__ cursor,
                       int* __restrict__ ssrc) {
    int e = blockIdx.x * 256 + threadIdx.x;
    if (e < E_EDGES) {
        int d = dst[e];
        int p = off[d] + atomicAdd(&cursor[d], 1);
        ssrc[p] = src[e];
    }
}

// ---------------- per-layer kernels ----------------

// feat[N,96] = h[N,K] @ W[K,96] + fused el/er computation.
template <int K>
__global__ __launch_bounds__(384) void k_gemm(const float* __restrict__ h,
                                              const float* __restrict__ W,
                                              const float* __restrict__ al_g,
                                              const float* __restrict__ ar_g,
                                              float* __restrict__ feat,
                                              float* __restrict__ el,
                                              float* __restrict__ er, int n) {
    constexpr int HL = 64 * K;
    constexpr int PT = 384 * 17;
    constexpr int SM = (HL > PT) ? HL : PT;
    __shared__ float smem[SM];
    float* hl = smem;

    int node0 = blockIdx.x * 64;
    int total4 = 64 * K / 4;
    for (int idx = threadIdx.x; idx < total4; idx += 384) {
        int node = idx / (K / 4);
        int koff = (idx % (K / 4)) * 4;
        float4 v = make_float4(0.f, 0.f, 0.f, 0.f);
        if (node0 + node < n)
            v = *(const float4*)(&h[(size_t)(node0 + node) * K + koff]);
        *(float4*)(&hl[node * K + koff]) = v;
    }
    __syncthreads();
    int grp = threadIdx.x / 48;        // 0..7
    int c = (threadIdx.x % 48) * 2;    // channel pair
    int nb = grp * 8;                  // 8 nodes per group
    float acc[8][2];
#pragma unroll
    for (int i = 0; i < 8; ++i) acc[i][0] = acc[i][1] = 0.f;
    for (int k = 0; k < K; k += 4) {
        float2 w0 = *(const float2*)&W[(k + 0) * 96 + c];
        float2 w1 = *(const float2*)&W[(k + 1) * 96 + c];
        float2 w2 = *(const float2*)&W[(k + 2) * 96 + c];
        float2 w3 = *(const float2*)&W[(k + 3) * 96 + c];
#pragma unroll
        for (int i = 0; i < 8; ++i) {
            float4 hv = *(const float4*)&hl[(nb + i) * K + k];
            acc[i][0] = fmaf(hv.x, w0.x, acc[i][0]);
            acc[i][1] = fmaf(hv.x, w0.y, acc[i][1]);
            acc[i][0] = fmaf(hv.y, w1.x, acc[i][0]);
            acc[i][1] = fmaf(hv.y, w1.y, acc[i][1]);
            acc[i][0] = fmaf(hv.z, w2.x, acc[i][0]);
            acc[i][1] = fmaf(hv.z, w2.y, acc[i][1]);
            acc[i][0] = fmaf(hv.w, w3.x, acc[i][0]);
            acc[i][1] = fmaf(hv.w, w3.y, acc[i][1]);
        }
    }
#pragma unroll
    for (int i = 0; i < 8; ++i) {
        int node = node0 + nb + i;
        if (node < n) *(float2*)&feat[(size_t)node * 96 + c] = make_float2(acc[i][0], acc[i][1]);
    }
    // el/er partials into reused LDS (pad 17 to spread banks)
    float alc0 = al_g[c], alc1 = al_g[c + 1];
    float arc0 = ar_g[c], arc1 = ar_g[c + 1];
    __syncthreads(); // all hl reads done; safe to reuse
    float* part = smem;
    int base = threadIdx.x * 17;
#pragma unroll
    for (int i = 0; i < 8; ++i) {
        part[base + i * 2]     = acc[i][0] * alc0 + acc[i][1] * alc1;
        part[base + i * 2 + 1] = acc[i][0] * arc0 + acc[i][1] * arc1;
    }
    __syncthreads();
    if (threadIdx.x < 256) {
        int ig = threadIdx.x >> 2;      // node in block (0..63)
        int hh = threadIdx.x & 3;       // head
        int g2 = ig >> 3, il = ig & 7;  // group, node-in-group
        float se = 0.f, sr = 0.f;
#pragma unroll
        for (int cc = 0; cc < 12; ++cc) {
            int t = g2 * 48 + hh * 12 + cc;
            se += part[t * 17 + il * 2];
            sr += part[t * 17 + il * 2 + 1];
        }
        int node = node0 + ig;
        if (node < n) {
            el[node * 4 + hh] = se;
            er[node * 4 + hh] = sr;
        }
    }
}

// per-node edge-softmax + aggregation: ONE WAVE PER NODE, no LDS, no barriers.
// lane = j0*8 + h*2 + half. __expf (v_exp_f32) + 32-bit byte-offset gathers.
__global__ __launch_bounds__(256) void k_agg(const int* __restrict__ off,
                                             const int* __restrict__ ssrc,
                                             const float* __restrict__ el,
                                             const float* __restrict__ er,
                                             const float* __restrict__ feat,
                                             const float* __restrict__ bias,
                                             float* __restrict__ out) {
    int n = blockIdx.x * 4 + (threadIdx.x >> 6);
    if (n >= N_NODES) return;
    int lane = threadIdx.x & 63;
    int j0   = lane >> 3;        // 0..7
    int h    = (lane >> 1) & 3;  // head
    int half = lane & 1;         // half of head's 24 channels
    int cbase = h * 24 + half * 12;
    unsigned cboff = (unsigned)cbase * 4u;

    int start = off[n], deg = off[n + 1] - start;
    float er_h = er[(unsigned)n * 4u + h];

    // ---- pass A: gather e into regs (up to 32 edges), running max
    float e_reg[4];
    unsigned s_reg[4];
    float lmax = -1e30f;
#pragma unroll
    for (int t = 0; t < 4; ++t) {
        int j = t * 8 + j0;
        bool act = (j < deg);
        unsigned s = act ? (unsigned)ssrc[start + j] : 0u;
        float e = -1e30f;
        if (act) {
            e = el[s * 4u + h] + er_h;
            e = (e > 0.f) ? e : NEG_SLOPE * e;
        }
        s_reg[t] = s;
        e_reg[t] = e;
        lmax = fmaxf(lmax, e);
    }
    for (int j = 32 + j0; j < deg; j += 8) {
        unsigned s = (unsigned)ssrc[start + j];
        float e = el[s * 4u + h] + er_h;
        e = (e > 0.f) ? e : NEG_SLOPE * e;
        lmax = fmaxf(lmax, e);
    }
    lmax = fmaxf(lmax, __shfl_xor(lmax, 8));
    lmax = fmaxf(lmax, __shfl_xor(lmax, 16));
    lmax = fmaxf(lmax, __shfl_xor(lmax, 32));
    float m = lmax;

    // ---- pass B: fused exp + denom + 12-channel accumulate
    float acc[12];
#pragma unroll
    for (int c = 0; c < 12; ++c) acc[c] = 0.f;
    float den = 0.f;
#pragma unroll
    for (int t = 0; t < 4; ++t) {
        int j = t * 8 + j0;
        if (j < deg) {
            float ex = __expf(e_reg[t] - m);
            den += ex;
            const float* fr = (const float*)((const char*)feat + (size_t)(s_reg[t] * 384u + cboff));
            float4 v0 = *(const float4*)(fr + 0);
            float4 v1 = *(const float4*)(fr + 4);
            float4 v2 = *(const float4*)(fr + 8);
            acc[0] = fmaf(ex, v0.x, acc[0]);  acc[1] = fmaf(ex, v0.y, acc[1]);
            acc[2] = fmaf(ex, v0.z, acc[2]);  acc[3] = fmaf(ex, v0.w, acc[3]);
            acc[4] = fmaf(ex, v1.x, acc[4]);  acc[5] = fmaf(ex, v1.y, acc[5]);
            acc[6] = fmaf(ex, v1.z, acc[6]);  acc[7] = fmaf(ex, v1.w, acc[7]);
            acc[8] = fmaf(ex, v2.x, acc[8]);  acc[9] = fmaf(ex, v2.y, acc[9]);
            acc[10] = fmaf(ex, v2.z, acc[10]); acc[11] = fmaf(ex, v2.w, acc[11]);
        }
    }
    for (int j = 32 + j0; j < deg; j += 8) {
        unsigned s = (unsigned)ssrc[start + j];
        float e = el[s * 4u + h] + er_h;
        e = (e > 0.f) ? e : NEG_SLOPE * e;
        float ex = __expf(e - m);
        den += ex;
        const float* fr = (const float*)((const char*)feat + (size_t)(s * 384u + cboff));
        float4 v0 = *(const float4*)(fr + 0);
        float4 v1 = *(const float4*)(fr + 4);
        float4 v2 = *(const float4*)(fr + 8);
        acc[0] = fmaf(ex, v0.x, acc[0]);  acc[1] = fmaf(ex, v0.y, acc[1]);
        acc[2] = fmaf(ex, v0.z, acc[2]);  acc[3] = fmaf(ex, v0.w, acc[3]);
        acc[4] = fmaf(ex, v1.x, acc[4]);  acc[5] = fmaf(ex, v1.y, acc[5]);
        acc[6] = fmaf(ex, v1.z, acc[6]);  acc[7] = fmaf(ex, v1.w, acc[7]);
        acc[8] = fmaf(ex, v2.x, acc[8]);  acc[9] = fmaf(ex, v2.y, acc[9]);
        acc[10] = fmaf(ex, v2.z, acc[10]); acc[11] = fmaf(ex, v2.w, acc[11]);
    }

    // ---- butterfly reduce over the 8 j-lanes (bits 3,4,5): 13 values
#pragma unroll
    for (int st = 8; st <= 32; st <<= 1) {
        den += __shfl_xor(den, st);
#pragma unroll
        for (int c = 0; c < 12; ++c) acc[c] += __shfl_xor(acc[c], st);
    }

    // ---- epilogue: lanes with j0==0 write their 12 channels
    if (j0 == 0) {
        float rden = (den > 0.f) ? 1.f / den : 0.f;
        const float* bp = &bias[cbase];
        float o[12];
#pragma unroll
        for (int c = 0; c < 12; ++c) {
            float v = acc[c] * rden + bp[c];
            o[c] = (v > 0.f) ? v : (__expf(v) - 1.f);
        }
        float* op = &out[(size_t)n * 96 + cbase];
        *(float4*)(op + 0) = make_float4(o[0], o[1], o[2], o[3]);
        *(float4*)(op + 4) = make_float4(o[4], o[5], o[6], o[7]);
        *(float4*)(op + 8) = make_float4(o[8], o[9], o[10], o[11]);
    }
}

// mean pool stage 1: block-partials, 4 rows x 96 channels per block
__global__ __launch_bounds__(384) void k_pool1(const float* __restrict__ h,
                                               float* __restrict__ partial) {
    int r = threadIdx.x / 96;   // 0..3
    int c = threadIdx.x % 96;
    float a = 0.f;
    for (int nrow = blockIdx.x * 4 + r; nrow < N_NODES; nrow += POOL_BLOCKS * 4)
        a += h[(size_t)nrow * 96 + c];
    __shared__ float sred[4][96];
    sred[r][c] = a;
    __syncthreads();
    if (r == 0)
        partial[blockIdx.x * 96 + c] = sred[0][c] + sred[1][c] + sred[2][c] + sred[3][c];
}

// mean pool stage 2: reduce partials, write out directly
__global__ __launch_bounds__(384) void k_pool2(const float* __restrict__ partial,
                                               float* __restrict__ out) {
    int g = threadIdx.x / 96;   // 0..3
    int c = threadIdx.x % 96;
    float a = 0.f;
    for (int b = g; b < POOL_BLOCKS; b += 4)
        a += partial[b * 96 + c];
    __shared__ float sred[4][96];
    sred[g][c] = a;
    __syncthreads();
    if (g == 0)
        out[c] = (sred[0][c] + sred[1][c] + sred[2][c] + sred[3][c]) * (1.0f / N_NODES);
}

// ---------------- launch ----------------

extern "C" void kernel_launch(void* const* d_in, const int* in_sizes, int n_in,
                              void* d_out, int out_size, void* d_ws, size_t ws_size,
                              hipStream_t stream) {
    const float* feats = (const float*)d_in[0];
    const int* src = (const int*)d_in[1];
    const int* dst = (const int*)d_in[2];

    char* p = (char*)d_ws;
    auto alloc = [&](size_t bytes) {
        void* r = (void*)p;
        p += (bytes + 255) & ~(size_t)255;
        return r;
    };
    float* A       = (float*)alloc((size_t)N_NODES * 96 * 4);
    float* B       = (float*)alloc((size_t)N_NODES * 96 * 4);
    float* el      = (float*)alloc((size_t)N_NODES * 4 * 4);
    float* er      = (float*)alloc((size_t)N_NODES * 4 * 4);
    int* degcur    = (int*)alloc((size_t)N_NODES * 2 * 4); // deg | cursor
    int* off       = (int*)alloc((size_t)(N_NODES + 1) * 4);
    int* bsum      = (int*)alloc((size_t)256 * 4);
    int* ssrc      = (int*)alloc((size_t)E_EDGES * 4);
    float* partial = (float*)alloc((size_t)POOL_BLOCKS * 96 * 4);
    int* deg = degcur;
    int* cursor = degcur + N_NODES;

    hipMemsetAsync(degcur, 0, (size_t)N_NODES * 2 * 4, stream);

    const int NB = (N_NODES + 255) / 256;
    k_hist<<<(E_EDGES + 255) / 256, 256, 0, stream>>>(dst, deg);
    k_scan1<<<NB, 256, 0, stream>>>(deg, bsum, N_NODES);
    k_scan3<<<NB, 256, 0, stream>>>(deg, bsum, off, N_NODES);
    k_fill<<<(E_EDGES + 255) / 256, 256, 0, stream>>>(src, dst, off, cursor, ssrc);

    const float* hin = feats;
    for (int l = 0; l < 3; ++l) {
        const float* W  = (const float*)d_in[3 + 4 * l];
        const float* al = (const float*)d_in[4 + 4 * l];
        const float* ar = (const float*)d_in[5 + 4 * l];
        const float* bb = (const float*)d_in[6 + 4 * l];

        if (l == 0)
            k_gemm<IN_DIM><<<(N_NODES + 63) / 64, 384, 0, stream>>>(hin, W, al, ar, B, el, er, N_NODES);
        else
            k_gemm<HIDDEN><<<(N_NODES + 63) / 64, 384, 0, stream>>>(hin, W, al, ar, B, el, er, N_NODES);

        k_agg<<<(N_NODES + 3) / 4, 256, 0, stream>>>(off, ssrc, el, er, B, bb, A);
        hin = A;
    }

    k_pool1<<<POOL_BLOCKS, 384, 0, stream>>>(A, partial);
    k_pool2<<<1, 384, 0, stream>>>(partial, (float*)d_out);
}